// Round 1
// baseline (34751.096 us; speedup 1.0000x reference)
//
#include <hip/hip_runtime.h>
#include <stdint.h>

#define B_ 32
#define T_ 256
#define DI_ 512
#define H_ 1024

using f32x4 = __attribute__((ext_vector_type(4))) float;
using s16x8 = __attribute__((ext_vector_type(8))) short;

__device__ inline unsigned short f2bf(float x) {
    unsigned u = __float_as_uint(x);
    u += 0x7FFFu + ((u >> 16) & 1u);
    return (unsigned short)(u >> 16);
}
__device__ inline float bf2f(unsigned short h) { return __uint_as_float(((unsigned)h) << 16); }
__device__ inline float sigf(float x) { return 1.f / (1.f + __expf(-x)); }
__device__ inline float tanhf_(float x) { return 1.f - 2.f / (__expf(2.f * x) + 1.f); }

// ---------------- conversion kernels ----------------

// inputs (B,T,DI) fp32 -> A0 [(t*B+b)][DI] bf16
__global__ void conv_inputs_k(const float* __restrict__ in, unsigned short* __restrict__ out) {
    int idx = blockIdx.x * 256 + threadIdx.x;      // one 4-elem group each; total 8192*512/4
    int d = (idx & 127) * 4;                       // 512/4 = 128 groups per row
    int row = idx >> 7;                            // row = t*32 + b
    int t = row >> 5, b = row & 31;
    float4 v = *(const float4*)(in + ((size_t)b * T_ + t) * DI_ + d);
    unsigned long long p = (unsigned long long)f2bf(v.x)
        | ((unsigned long long)f2bf(v.y) << 16)
        | ((unsigned long long)f2bf(v.z) << 32)
        | ((unsigned long long)f2bf(v.w) << 48);
    *(unsigned long long*)(out + (size_t)row * DI_ + d) = p;
}

// generic fp32 [R][rowStride] (col offset) -> bf16 [R][K]
__global__ void conv_w_k(const float* __restrict__ src, unsigned short* __restrict__ dst,
                         int rowStride, int colOff, int K, int total4) {
    int idx = blockIdx.x * 256 + threadIdx.x;
    if (idx >= total4) return;
    int K4 = K >> 2;
    int r = idx / K4;
    int k = (idx - r * K4) << 2;
    float4 v = *(const float4*)(src + (size_t)r * rowStride + colOff + k);
    unsigned long long p = (unsigned long long)f2bf(v.x)
        | ((unsigned long long)f2bf(v.y) << 16)
        | ((unsigned long long)f2bf(v.z) << 32)
        | ((unsigned long long)f2bf(v.w) << 48);
    *(unsigned long long*)(dst + (size_t)r * K + k) = p;
}

__global__ void bias0_k(const float* __restrict__ a, const float* __restrict__ b, float* __restrict__ o) {
    int i = blockIdx.x * 256 + threadIdx.x;
    if (i < 4 * H_) o[i] = a[i] + b[i];
}

// ---------------- big parallel projection GEMM ----------------
// out[M][N] (bf16) = A[M][K](bf16) * W[N][K]^T (bf16) + bias[N]
// 128x128 tile, 256 threads (4 waves, each 64x64), K-step 32, mfma 16x16x32 bf16.
__global__ __launch_bounds__(256) void proj_gemm_k(
    const unsigned short* __restrict__ A, const unsigned short* __restrict__ W,
    const float* __restrict__ bias, unsigned short* __restrict__ out, int K, int N) {
    __shared__ unsigned short Al[128 * 56];
    __shared__ unsigned short Bl[128 * 56];
    const int tid = threadIdx.x;
    const int lane = tid & 63, wave = tid >> 6;
    const int quad = lane >> 4, l16 = lane & 15;
    const int wm = (wave >> 1) * 64, wn = (wave & 1) * 64;
    const int bm = blockIdx.x, bn = blockIdx.y;
    const int srow = tid >> 1, shalf = tid & 1;
    const unsigned short* Ab = A + (size_t)(bm * 128 + srow) * K + shalf * 16;
    const unsigned short* Wb = W + (size_t)(bn * 128 + srow) * K + shalf * 16;

    f32x4 acc[4][4];
#pragma unroll
    for (int i = 0; i < 4; i++)
#pragma unroll
        for (int j = 0; j < 4; j++) acc[i][j] = (f32x4){0.f, 0.f, 0.f, 0.f};

    for (int kb = 0; kb < K; kb += 32) {
        s16x8 a0 = *(const s16x8*)(Ab + kb);
        s16x8 a1 = *(const s16x8*)(Ab + kb + 8);
        s16x8 b0 = *(const s16x8*)(Wb + kb);
        s16x8 b1 = *(const s16x8*)(Wb + kb + 8);
        __syncthreads();
        *(s16x8*)(&Al[srow * 56 + shalf * 16]) = a0;
        *(s16x8*)(&Al[srow * 56 + shalf * 16 + 8]) = a1;
        *(s16x8*)(&Bl[srow * 56 + shalf * 16]) = b0;
        *(s16x8*)(&Bl[srow * 56 + shalf * 16 + 8]) = b1;
        __syncthreads();
        s16x8 af[4], bf[4];
#pragma unroll
        for (int mt = 0; mt < 4; mt++) af[mt] = *(const s16x8*)(&Al[(wm + mt * 16 + l16) * 56 + quad * 8]);
#pragma unroll
        for (int nt = 0; nt < 4; nt++) bf[nt] = *(const s16x8*)(&Bl[(wn + nt * 16 + l16) * 56 + quad * 8]);
#pragma unroll
        for (int mt = 0; mt < 4; mt++)
#pragma unroll
            for (int nt = 0; nt < 4; nt++)
                acc[mt][nt] = __builtin_amdgcn_mfma_f32_16x16x32_bf16(af[mt], bf[nt], acc[mt][nt], 0, 0, 0);
    }
#pragma unroll
    for (int nt = 0; nt < 4; nt++) {
        int col = bn * 128 + wn + nt * 16 + l16;
        float bv = bias[col];
#pragma unroll
        for (int mt = 0; mt < 4; mt++) {
#pragma unroll
            for (int r = 0; r < 4; r++) {
                int rowg = bm * 128 + wm + mt * 16 + quad * 4 + r;
                out[(size_t)rowg * N + col] = f2bf(acc[mt][nt][r] + bv);
            }
        }
    }
}

// ---------------- persistent recurrence kernel ----------------
// 256 WGs x 256 threads. WG owns 4 hidden units (NG gate-rows each).
// Weights (fp32 global) -> bf16 LDS rows (stride 1032, +1 zero row).
// Per step: barrier (flag array) -> MFMA gates = h_{t-1} @ W^T -> pointwise -> publish h.
template <int NG, bool CA, bool WROUT>
__global__ __launch_bounds__(256) void rec_k(
    const float* __restrict__ Wsrc, int wRowStride, int wColOff,
    const unsigned short* __restrict__ pre, int N,
    const unsigned short* __restrict__ clow,
    unsigned short* __restrict__ hbuf,
    unsigned short* __restrict__ cbuf,
    float* __restrict__ outh, float* __restrict__ outc,
    unsigned* __restrict__ flags) {
    constexpr int ROWS = NG * 4;
    __shared__ unsigned short wl[(ROWS + 1) * 1032];
    __shared__ float gl[32 * 24];
    const int tid = threadIdx.x;
    const int wg = blockIdx.x;
    const int lane = tid & 63, wave = tid >> 6;
    const int quad = lane >> 4, l16 = lane & 15;

    // load + convert this WG's weight rows into LDS
    for (int i = tid; i < ROWS * 1024; i += 256) {
        int r = i >> 10, k = i & 1023;
        int g = r >> 2, u = r & 3;
        float wv = Wsrc[(size_t)(g * H_ + wg * 4 + u) * wRowStride + wColOff + k];
        wl[r * 1032 + k] = f2bf(wv);
    }
    for (int k = tid; k < 1032; k += 256) wl[ROWS * 1032 + k] = 0;
    __syncthreads();

    const int mtile = wave & 1;
    const int ntile = wave >> 1;
    const bool active = (ntile * 16) < ROWS;
    int brow = ntile * 16 + l16;
    if (brow >= ROWS) brow = ROWS;  // zero row for padded N-columns

    const int u = tid & 3, b = tid >> 2;  // pointwise ownership (tid < 128)
    const int unit = wg * 4 + u;
    float cst = 0.f;
    unsigned short pg[NG];
    unsigned short clw = 0;
    if (tid < 128) {
#pragma unroll
        for (int g = 0; g < NG; g++) pg[g] = pre[(size_t)b * N + g * H_ + unit];
        if (CA) clw = clow[(size_t)b * H_ + unit];
    }

    for (int t = 0; t < T_; ++t) {
        if (t > 0) {
            unsigned tgt = (unsigned)t;
            for (;;) {
                unsigned f0 = __hip_atomic_load(&flags[lane * 4 + 0], __ATOMIC_RELAXED, __HIP_MEMORY_SCOPE_AGENT);
                unsigned f1 = __hip_atomic_load(&flags[lane * 4 + 1], __ATOMIC_RELAXED, __HIP_MEMORY_SCOPE_AGENT);
                unsigned f2 = __hip_atomic_load(&flags[lane * 4 + 2], __ATOMIC_RELAXED, __HIP_MEMORY_SCOPE_AGENT);
                unsigned f3 = __hip_atomic_load(&flags[lane * 4 + 3], __ATOMIC_RELAXED, __HIP_MEMORY_SCOPE_AGENT);
                unsigned m01 = f0 < f1 ? f0 : f1;
                unsigned m23 = f2 < f3 ? f2 : f3;
                unsigned mn = m01 < m23 ? m01 : m23;
                if (__all((int)(mn >= tgt))) break;
                __builtin_amdgcn_s_sleep(1);
            }
            __threadfence();  // acquire: invalidate caches so h_{t-1} reads are fresh
            if (active) {
                f32x4 acc = (f32x4){0.f, 0.f, 0.f, 0.f};
                const unsigned short* hrow = hbuf + ((size_t)(t - 1) * B_ + mtile * 16 + l16) * H_;
                const unsigned short* wrow = &wl[brow * 1032];
#pragma unroll 8
                for (int kb = 0; kb < H_; kb += 32) {
                    s16x8 af = *(const s16x8*)(hrow + kb + quad * 8);
                    s16x8 bf = *(const s16x8*)(wrow + kb + quad * 8);
                    acc = __builtin_amdgcn_mfma_f32_16x16x32_bf16(af, bf, acc, 0, 0, 0);
                }
                int n = ntile * 16 + l16;
                if (n < ROWS) {
#pragma unroll
                    for (int r = 0; r < 4; r++) gl[(mtile * 16 + quad * 4 + r) * 24 + n] = acc[r];
                }
            }
        }
        __syncthreads();
        if (tid < 128) {
            float gate[NG];
#pragma unroll
            for (int g = 0; g < NG; g++)
                gate[g] = bf2f(pg[g]) + ((t > 0) ? gl[b * 24 + g * 4 + u] : 0.f);
            float clv = CA ? bf2f(clw) : 0.f;
            if (t + 1 < T_) {  // prefetch next step's pre / c_low (hides HBM latency)
#pragma unroll
                for (int g = 0; g < NG; g++) pg[g] = pre[(size_t)((t + 1) * B_ + b) * N + g * H_ + unit];
                if (CA) clw = clow[(size_t)((t + 1) * B_ + b) * H_ + unit];
            }
            float cnew, hval;
            if (CA) {
                float iv = sigf(gate[0]);
                float fp = sigf(gate[1] + 1.f);
                float fl = sigf(gate[2] + 1.f);
                float uu = tanhf_(gate[3]);
                float ov = sigf(gate[4]);
                cnew = cst * fp + clv * fl + uu * iv;
                hval = ov * tanhf_(cnew);
            } else {
                float iv = sigf(gate[0]);
                float fv = sigf(gate[1]);
                float gv = tanhf_(gate[2]);
                float ov = sigf(gate[3]);
                cnew = fv * cst + iv * gv;
                hval = ov * tanhf_(cnew);
            }
            cst = cnew;
            size_t ridx = ((size_t)t * B_ + b) * H_ + unit;
            hbuf[ridx] = f2bf(hval);
            if (cbuf) cbuf[ridx] = f2bf(cnew);
            if (WROUT) {
                outh[((size_t)b * T_ + t) * H_ + unit] = hval;
                outc[((size_t)b * T_ + t) * H_ + unit] = cnew;
            }
        }
        __syncthreads();  // drains all waves' vmcnt: h stores are in L2 before release
        if (tid == 0) {
            __threadfence();  // agent release: write back L2 so other XCDs see h
            __hip_atomic_store(&flags[wg], (unsigned)(t + 1), __ATOMIC_RELAXED, __HIP_MEMORY_SCOPE_AGENT);
        }
    }
}

// ---------------- launcher ----------------

extern "C" void kernel_launch(void* const* d_in, const int* in_sizes, int n_in,
                              void* d_out, int out_size, void* d_ws, size_t ws_size,
                              hipStream_t stream) {
    const float* inputs = (const float*)d_in[0];
    const float* W_ih0 = (const float*)d_in[1];
    const float* W_hh0 = (const float*)d_in[2];
    const float* b_ih0 = (const float*)d_in[3];
    const float* b_hh0 = (const float*)d_in[4];
    const float* W_ca = (const float*)d_in[5];
    const float* b_ca = (const float*)d_in[6];
    float* out = (float*)d_out;

    char* ws = (char*)d_ws;
    unsigned* flags = (unsigned*)(ws);                                       //  4 KB (4 x 256 flags)
    unsigned short* A0 = (unsigned short*)(ws + 4096);                       //  8 MB
    unsigned short* Wbuf = (unsigned short*)(ws + 4096 + 8388608);           // 10.5 MB
    float* bc0 = (float*)(ws + 4096 + 8388608 + 10485760);                   // 16 KB
    unsigned short* pre = (unsigned short*)(ws + 4096 + 8388608 + 10485760 + 16384);  // 84 MB
    unsigned short* hA = pre + (size_t)8192 * 5120;
    unsigned short* hB = hA + (size_t)8192 * 1024;
    unsigned short* cA = hB + (size_t)8192 * 1024;
    unsigned short* cB = cA + (size_t)8192 * 1024;

    hipMemsetAsync(flags, 0, 4096, stream);

    // layer 0
    conv_inputs_k<<<4096, 256, 0, stream>>>(inputs, A0);
    conv_w_k<<<2048, 256, 0, stream>>>(W_ih0, Wbuf, 512, 0, 512, 4096 * 128);
    bias0_k<<<16, 256, 0, stream>>>(b_ih0, b_hh0, bc0);
    proj_gemm_k<<<dim3(64, 32), 256, 0, stream>>>(A0, Wbuf, bc0, pre, 512, 4096);
    rec_k<4, false, false><<<256, 256, 0, stream>>>(W_hh0, 1024, 0, pre, 4096, nullptr,
                                                    hA, cA, nullptr, nullptr, flags + 0);
    // layer 1
    conv_w_k<<<5120, 256, 0, stream>>>(W_ca + (size_t)0 * 5120 * 2048, Wbuf, 2048, 0, 1024, 5120 * 256);
    proj_gemm_k<<<dim3(64, 40), 256, 0, stream>>>(hA, Wbuf, b_ca + 0 * 5120, pre, 1024, 5120);
    rec_k<5, true, false><<<256, 256, 0, stream>>>(W_ca + (size_t)0 * 5120 * 2048, 2048, 1024, pre, 5120,
                                                   cA, hB, cB, nullptr, nullptr, flags + 256);
    // layer 2
    conv_w_k<<<5120, 256, 0, stream>>>(W_ca + (size_t)1 * 5120 * 2048, Wbuf, 2048, 0, 1024, 5120 * 256);
    proj_gemm_k<<<dim3(64, 40), 256, 0, stream>>>(hB, Wbuf, b_ca + 1 * 5120, pre, 1024, 5120);
    rec_k<5, true, false><<<256, 256, 0, stream>>>(W_ca + (size_t)1 * 5120 * 2048, 2048, 1024, pre, 5120,
                                                   cB, hA, cA, nullptr, nullptr, flags + 512);
    // layer 3 (writes d_out directly: hs then cs, (B,T,H) fp32)
    conv_w_k<<<5120, 256, 0, stream>>>(W_ca + (size_t)2 * 5120 * 2048, Wbuf, 2048, 0, 1024, 5120 * 256);
    proj_gemm_k<<<dim3(64, 40), 256, 0, stream>>>(hA, Wbuf, b_ca + 2 * 5120, pre, 1024, 5120);
    rec_k<5, true, true><<<256, 256, 0, stream>>>(W_ca + (size_t)2 * 5120 * 2048, 2048, 1024, pre, 5120,
                                                  cA, hB, nullptr, out, out + (size_t)8192 * 1024, flags + 768);
}

// Round 2
// 12649.587 us; speedup vs baseline: 2.7472x; 2.7472x over previous
//
#include <hip/hip_runtime.h>
#include <stdint.h>

#define B_ 32
#define T_ 256
#define DI_ 512
#define H_ 1024

using f32x4 = __attribute__((ext_vector_type(4))) float;
using s16x8 = __attribute__((ext_vector_type(8))) short;

__device__ inline unsigned short f2bf(float x) {
    unsigned u = __float_as_uint(x);
    u += 0x7FFFu + ((u >> 16) & 1u);
    return (unsigned short)(u >> 16);
}
__device__ inline float bf2f(unsigned short h) { return __uint_as_float(((unsigned)h) << 16); }
__device__ inline float sigf(float x) { return 1.f / (1.f + __expf(-x)); }
__device__ inline float tanhf_(float x) { return 1.f - 2.f / (__expf(2.f * x) + 1.f); }

// coherent (agent-scope, sc1) 16B load: 2 x 8B relaxed atomic loads.
// Bypasses the non-coherent per-XCD L2 -> reads LLC. No fence needed.
__device__ inline s16x8 ld16c(const unsigned short* p) {
    union { unsigned long long u[2]; s16x8 v; } r;
    const unsigned long long* q = (const unsigned long long*)p;
    r.u[0] = __hip_atomic_load(q, __ATOMIC_RELAXED, __HIP_MEMORY_SCOPE_AGENT);
    r.u[1] = __hip_atomic_load(q + 1, __ATOMIC_RELAXED, __HIP_MEMORY_SCOPE_AGENT);
    return r.v;
}

// ---------------- conversion kernels ----------------

// inputs (B,T,DI) fp32 -> A0 [(t*B+b)][DI] bf16
__global__ void conv_inputs_k(const float* __restrict__ in, unsigned short* __restrict__ out) {
    int idx = blockIdx.x * 256 + threadIdx.x;
    int d = (idx & 127) * 4;
    int row = idx >> 7;
    int t = row >> 5, b = row & 31;
    float4 v = *(const float4*)(in + ((size_t)b * T_ + t) * DI_ + d);
    unsigned long long p = (unsigned long long)f2bf(v.x)
        | ((unsigned long long)f2bf(v.y) << 16)
        | ((unsigned long long)f2bf(v.z) << 32)
        | ((unsigned long long)f2bf(v.w) << 48);
    *(unsigned long long*)(out + (size_t)row * DI_ + d) = p;
}

// generic fp32 [R][rowStride] (col offset) -> bf16 [R][K]
__global__ void conv_w_k(const float* __restrict__ src, unsigned short* __restrict__ dst,
                         int rowStride, int colOff, int K, int total4) {
    int idx = blockIdx.x * 256 + threadIdx.x;
    if (idx >= total4) return;
    int K4 = K >> 2;
    int r = idx / K4;
    int k = (idx - r * K4) << 2;
    float4 v = *(const float4*)(src + (size_t)r * rowStride + colOff + k);
    unsigned long long p = (unsigned long long)f2bf(v.x)
        | ((unsigned long long)f2bf(v.y) << 16)
        | ((unsigned long long)f2bf(v.z) << 32)
        | ((unsigned long long)f2bf(v.w) << 48);
    *(unsigned long long*)(dst + (size_t)r * K + k) = p;
}

__global__ void bias0_k(const float* __restrict__ a, const float* __restrict__ b, float* __restrict__ o) {
    int i = blockIdx.x * 256 + threadIdx.x;
    if (i < 4 * H_) o[i] = a[i] + b[i];
}

// ---------------- big parallel projection GEMM ----------------
__global__ __launch_bounds__(256) void proj_gemm_k(
    const unsigned short* __restrict__ A, const unsigned short* __restrict__ W,
    const float* __restrict__ bias, unsigned short* __restrict__ out, int K, int N) {
    __shared__ unsigned short Al[128 * 56];
    __shared__ unsigned short Bl[128 * 56];
    const int tid = threadIdx.x;
    const int lane = tid & 63, wave = tid >> 6;
    const int quad = lane >> 4, l16 = lane & 15;
    const int wm = (wave >> 1) * 64, wn = (wave & 1) * 64;
    const int bm = blockIdx.x, bn = blockIdx.y;
    const int srow = tid >> 1, shalf = tid & 1;
    const unsigned short* Ab = A + (size_t)(bm * 128 + srow) * K + shalf * 16;
    const unsigned short* Wb = W + (size_t)(bn * 128 + srow) * K + shalf * 16;

    f32x4 acc[4][4];
#pragma unroll
    for (int i = 0; i < 4; i++)
#pragma unroll
        for (int j = 0; j < 4; j++) acc[i][j] = (f32x4){0.f, 0.f, 0.f, 0.f};

    for (int kb = 0; kb < K; kb += 32) {
        s16x8 a0 = *(const s16x8*)(Ab + kb);
        s16x8 a1 = *(const s16x8*)(Ab + kb + 8);
        s16x8 b0 = *(const s16x8*)(Wb + kb);
        s16x8 b1 = *(const s16x8*)(Wb + kb + 8);
        __syncthreads();
        *(s16x8*)(&Al[srow * 56 + shalf * 16]) = a0;
        *(s16x8*)(&Al[srow * 56 + shalf * 16 + 8]) = a1;
        *(s16x8*)(&Bl[srow * 56 + shalf * 16]) = b0;
        *(s16x8*)(&Bl[srow * 56 + shalf * 16 + 8]) = b1;
        __syncthreads();
        s16x8 af[4], bf[4];
#pragma unroll
        for (int mt = 0; mt < 4; mt++) af[mt] = *(const s16x8*)(&Al[(wm + mt * 16 + l16) * 56 + quad * 8]);
#pragma unroll
        for (int nt = 0; nt < 4; nt++) bf[nt] = *(const s16x8*)(&Bl[(wn + nt * 16 + l16) * 56 + quad * 8]);
#pragma unroll
        for (int mt = 0; mt < 4; mt++)
#pragma unroll
            for (int nt = 0; nt < 4; nt++)
                acc[mt][nt] = __builtin_amdgcn_mfma_f32_16x16x32_bf16(af[mt], bf[nt], acc[mt][nt], 0, 0, 0);
    }
#pragma unroll
    for (int nt = 0; nt < 4; nt++) {
        int col = bn * 128 + wn + nt * 16 + l16;
        float bv = bias[col];
#pragma unroll
        for (int mt = 0; mt < 4; mt++) {
#pragma unroll
            for (int r = 0; r < 4; r++) {
                int rowg = bm * 128 + wm + mt * 16 + quad * 4 + r;
                out[(size_t)rowg * N + col] = f2bf(acc[mt][nt][r] + bv);
            }
        }
    }
}

// ---------------- persistent recurrence kernel (fence-free) ----------------
// h exchange is done with relaxed AGENT-scope atomics (sc1: coherent at LLC,
// bypasses per-XCD L2) => no __threadfence (no buffer_inv/wbl2 L2 thrash).
// Release ordering: s_waitcnt vmcnt(0) between h stores and flag store.
template <int NG, bool CA, bool WROUT>
__global__ __launch_bounds__(256) void rec_k(
    const float* __restrict__ Wsrc, int wRowStride, int wColOff,
    const unsigned short* __restrict__ pre, int N,
    const unsigned short* __restrict__ clow,
    unsigned short* __restrict__ hbuf,
    unsigned short* __restrict__ cbuf,
    float* __restrict__ outh, float* __restrict__ outc,
    unsigned* __restrict__ flags) {
    constexpr int ROWS = NG * 4;
    __shared__ unsigned short wl[(ROWS + 1) * 1032];
    __shared__ float gl[32 * 24];
    __shared__ alignas(8) unsigned short hsh[128];
    const int tid = threadIdx.x;
    const int wg = blockIdx.x;
    const int lane = tid & 63, wave = tid >> 6;
    const int quad = lane >> 4, l16 = lane & 15;

    // load + convert this WG's weight rows into LDS
    for (int i = tid; i < ROWS * 1024; i += 256) {
        int r = i >> 10, k = i & 1023;
        int g = r >> 2, u = r & 3;
        float wv = Wsrc[(size_t)(g * H_ + wg * 4 + u) * wRowStride + wColOff + k];
        wl[r * 1032 + k] = f2bf(wv);
    }
    for (int k = tid; k < 1032; k += 256) wl[ROWS * 1032 + k] = 0;
    __syncthreads();

    const int mtile = wave & 1;
    const int ntile = wave >> 1;
    const bool active = (ntile * 16) < ROWS;
    int brow = ntile * 16 + l16;
    if (brow >= ROWS) brow = ROWS;  // zero row for padded N-columns

    const int u = tid & 3, b = tid >> 2;  // pointwise ownership (tid < 128)
    const int unit = wg * 4 + u;
    float cst = 0.f;
    unsigned short pg[NG];
    unsigned short clw = 0;
    if (tid < 128) {
#pragma unroll
        for (int g = 0; g < NG; g++) pg[g] = pre[(size_t)b * N + g * H_ + unit];
        if (CA) clw = clow[(size_t)b * H_ + unit];
    }

    for (int t = 0; t < T_; ++t) {
        if (t > 0) {
            unsigned tgt = (unsigned)t;
            const unsigned long long* fq = (const unsigned long long*)&flags[lane * 4];
            for (;;) {
                unsigned long long f01 = __hip_atomic_load(fq, __ATOMIC_RELAXED, __HIP_MEMORY_SCOPE_AGENT);
                unsigned long long f23 = __hip_atomic_load(fq + 1, __ATOMIC_RELAXED, __HIP_MEMORY_SCOPE_AGENT);
                unsigned a = (unsigned)f01, bb = (unsigned)(f01 >> 32);
                unsigned c = (unsigned)f23, d = (unsigned)(f23 >> 32);
                unsigned m01 = a < bb ? a : bb;
                unsigned m23 = c < d ? c : d;
                unsigned mn = m01 < m23 ? m01 : m23;
                if (__all((int)(mn >= tgt))) break;
                __builtin_amdgcn_s_sleep(1);
            }
            asm volatile("" ::: "memory");  // compiler barrier: keep h loads after poll
            if (active) {
                const unsigned short* hrow = hbuf + ((size_t)(t - 1) * B_ + mtile * 16 + l16) * H_ + quad * 8;
                const unsigned short* wrow = &wl[brow * 1032 + quad * 8];
                f32x4 a0 = (f32x4){0.f, 0.f, 0.f, 0.f};
                f32x4 a1 = a0, a2 = a0, a3 = a0;
#pragma unroll
                for (int kb = 0; kb < H_; kb += 128) {
                    s16x8 h0 = ld16c(hrow + kb);
                    s16x8 h1 = ld16c(hrow + kb + 32);
                    s16x8 h2 = ld16c(hrow + kb + 64);
                    s16x8 h3 = ld16c(hrow + kb + 96);
                    a0 = __builtin_amdgcn_mfma_f32_16x16x32_bf16(h0, *(const s16x8*)(wrow + kb), a0, 0, 0, 0);
                    a1 = __builtin_amdgcn_mfma_f32_16x16x32_bf16(h1, *(const s16x8*)(wrow + kb + 32), a1, 0, 0, 0);
                    a2 = __builtin_amdgcn_mfma_f32_16x16x32_bf16(h2, *(const s16x8*)(wrow + kb + 64), a2, 0, 0, 0);
                    a3 = __builtin_amdgcn_mfma_f32_16x16x32_bf16(h3, *(const s16x8*)(wrow + kb + 96), a3, 0, 0, 0);
                }
                f32x4 acc = (a0 + a1) + (a2 + a3);
                int n = ntile * 16 + l16;
                if (n < ROWS) {
#pragma unroll
                    for (int r = 0; r < 4; r++) gl[(mtile * 16 + quad * 4 + r) * 24 + n] = acc[r];
                }
            }
        }
        __syncthreads();
        if (tid < 128) {
            float gate[NG];
#pragma unroll
            for (int g = 0; g < NG; g++)
                gate[g] = bf2f(pg[g]) + ((t > 0) ? gl[b * 24 + g * 4 + u] : 0.f);
            float clv = CA ? bf2f(clw) : 0.f;
            if (t + 1 < T_) {  // prefetch next step's pre / c_low
#pragma unroll
                for (int g = 0; g < NG; g++) pg[g] = pre[(size_t)((t + 1) * B_ + b) * N + g * H_ + unit];
                if (CA) clw = clow[(size_t)((t + 1) * B_ + b) * H_ + unit];
            }
            float cnew, hval;
            if (CA) {
                float iv = sigf(gate[0]);
                float fp = sigf(gate[1] + 1.f);
                float fl = sigf(gate[2] + 1.f);
                float uu = tanhf_(gate[3]);
                float ov = sigf(gate[4]);
                cnew = cst * fp + clv * fl + uu * iv;
                hval = ov * tanhf_(cnew);
            } else {
                float iv = sigf(gate[0]);
                float fv = sigf(gate[1]);
                float gv = tanhf_(gate[2]);
                float ov = sigf(gate[3]);
                cnew = fv * cst + iv * gv;
                hval = ov * tanhf_(cnew);
            }
            cst = cnew;
            hsh[tid] = f2bf(hval);
            size_t ridx = ((size_t)t * B_ + b) * H_ + unit;
            if (cbuf) cbuf[ridx] = f2bf(cnew);  // plain store: consumed by a later dispatch only
            if (WROUT) {
                outh[((size_t)b * T_ + t) * H_ + unit] = hval;
                outc[((size_t)b * T_ + t) * H_ + unit] = cnew;
            }
        }
        __syncthreads();
        // wave 0: pack 4 bf16 -> 8B coherent store, then release via vmcnt(0) + flag
        if (tid < 32) {
            unsigned long long pk = *(const unsigned long long*)(&hsh[tid * 4]);
            unsigned long long* dst = (unsigned long long*)(hbuf + ((size_t)t * B_ + tid) * H_ + wg * 4);
            __hip_atomic_store(dst, pk, __ATOMIC_RELAXED, __HIP_MEMORY_SCOPE_AGENT);
        }
        if (wave == 0) {
            asm volatile("s_waitcnt vmcnt(0)" ::: "memory");  // h stores visible at LLC
            if (tid == 0)
                __hip_atomic_store(&flags[wg], (unsigned)(t + 1), __ATOMIC_RELAXED, __HIP_MEMORY_SCOPE_AGENT);
        }
    }
}

// ---------------- launcher ----------------

extern "C" void kernel_launch(void* const* d_in, const int* in_sizes, int n_in,
                              void* d_out, int out_size, void* d_ws, size_t ws_size,
                              hipStream_t stream) {
    const float* inputs = (const float*)d_in[0];
    const float* W_ih0 = (const float*)d_in[1];
    const float* W_hh0 = (const float*)d_in[2];
    const float* b_ih0 = (const float*)d_in[3];
    const float* b_hh0 = (const float*)d_in[4];
    const float* W_ca = (const float*)d_in[5];
    const float* b_ca = (const float*)d_in[6];
    float* out = (float*)d_out;

    char* ws = (char*)d_ws;
    unsigned* flags = (unsigned*)(ws);                                       //  4 KB
    unsigned short* A0 = (unsigned short*)(ws + 4096);                       //  8 MB
    unsigned short* Wbuf = (unsigned short*)(ws + 4096 + 8388608);           // 10.5 MB
    float* bc0 = (float*)(ws + 4096 + 8388608 + 10485760);                   // 16 KB
    unsigned short* pre = (unsigned short*)(ws + 4096 + 8388608 + 10485760 + 16384);  // 84 MB
    unsigned short* hA = pre + (size_t)8192 * 5120;
    unsigned short* hB = hA + (size_t)8192 * 1024;
    unsigned short* cA = hB + (size_t)8192 * 1024;
    unsigned short* cB = cA + (size_t)8192 * 1024;

    hipMemsetAsync(flags, 0, 4096, stream);

    // layer 0
    conv_inputs_k<<<4096, 256, 0, stream>>>(inputs, A0);
    conv_w_k<<<2048, 256, 0, stream>>>(W_ih0, Wbuf, 512, 0, 512, 4096 * 128);
    bias0_k<<<16, 256, 0, stream>>>(b_ih0, b_hh0, bc0);
    proj_gemm_k<<<dim3(64, 32), 256, 0, stream>>>(A0, Wbuf, bc0, pre, 512, 4096);
    rec_k<4, false, false><<<256, 256, 0, stream>>>(W_hh0, 1024, 0, pre, 4096, nullptr,
                                                    hA, cA, nullptr, nullptr, flags + 0);
    // layer 1
    conv_w_k<<<5120, 256, 0, stream>>>(W_ca + (size_t)0 * 5120 * 2048, Wbuf, 2048, 0, 1024, 5120 * 256);
    proj_gemm_k<<<dim3(64, 40), 256, 0, stream>>>(hA, Wbuf, b_ca + 0 * 5120, pre, 1024, 5120);
    rec_k<5, true, false><<<256, 256, 0, stream>>>(W_ca + (size_t)0 * 5120 * 2048, 2048, 1024, pre, 5120,
                                                   cA, hB, cB, nullptr, nullptr, flags + 256);
    // layer 2
    conv_w_k<<<5120, 256, 0, stream>>>(W_ca + (size_t)1 * 5120 * 2048, Wbuf, 2048, 0, 1024, 5120 * 256);
    proj_gemm_k<<<dim3(64, 40), 256, 0, stream>>>(hB, Wbuf, b_ca + 1 * 5120, pre, 1024, 5120);
    rec_k<5, true, false><<<256, 256, 0, stream>>>(W_ca + (size_t)1 * 5120 * 2048, 2048, 1024, pre, 5120,
                                                   cB, hA, cA, nullptr, nullptr, flags + 512);
    // layer 3 (writes d_out directly: hs then cs, (B,T,H) fp32)
    conv_w_k<<<5120, 256, 0, stream>>>(W_ca + (size_t)2 * 5120 * 2048, Wbuf, 2048, 0, 1024, 5120 * 256);
    proj_gemm_k<<<dim3(64, 40), 256, 0, stream>>>(hA, Wbuf, b_ca + 2 * 5120, pre, 1024, 5120);
    rec_k<5, true, true><<<256, 256, 0, stream>>>(W_ca + (size_t)2 * 5120 * 2048, 2048, 1024, pre, 5120,
                                                  cA, hB, nullptr, out, out + (size_t)8192 * 1024, flags + 768);
}